// Round 15
// baseline (463.775 us; speedup 1.0000x reference)
//
#include <hip/hip_runtime.h>
#include <math.h>

#define NNODES 50000
#define MPAD   50048    // NNODES rounded up to 128
#define D      256
#define K2     512
#define NEDGES 300000
#define NGRAPH 512
#define NLAYERS 3

#define SCB    256
#define NSCB   ((NNODES + SCB - 1) / SCB)   // 196 blocks

typedef __bf16 bf16x8 __attribute__((ext_vector_type(8)));
typedef float  f32x4  __attribute__((ext_vector_type(4)));

__device__ __forceinline__ ushort f2bf(float f) {
    unsigned u = __float_as_uint(f);
    unsigned r = (u + 0x7FFFu + ((u >> 16) & 1u)) >> 16;   // RNE
    return (ushort)r;
}
__device__ __forceinline__ float bf2f(ushort b) {
    return __uint_as_float(((unsigned)b) << 16);
}

__device__ __forceinline__ void stage16(const ushort* g, ushort* l) {
    __builtin_amdgcn_global_load_lds(
        (const __attribute__((address_space(1))) unsigned*)g,
        (__attribute__((address_space(3))) unsigned*)l, 16, 0, 0);
}

// ---------------- CSR build ----------------
__global__ __launch_bounds__(256)
void hist_kernel(const int* __restrict__ dst, int* __restrict__ deg, int nE) {
    int e = blockIdx.x * 256 + threadIdx.x;
    if (e < nE) atomicAdd(&deg[dst[e]], 1);
}

__global__ __launch_bounds__(SCB)
void scan_part_kernel(const int* __restrict__ deg, int* __restrict__ bsum) {
    __shared__ int red[SCB];
    int t = threadIdx.x;
    int i = blockIdx.x * SCB + t;
    red[t] = (i < NNODES) ? deg[i] : 0;
    __syncthreads();
#pragma unroll
    for (int off = SCB / 2; off > 0; off >>= 1) {
        if (t < off) red[t] += red[t + off];
        __syncthreads();
    }
    if (t == 0) bsum[blockIdx.x] = red[0];
}

__global__ __launch_bounds__(256)
void scan_bsum_kernel(const int* __restrict__ bsum, int* __restrict__ boff) {
    __shared__ int p[256];
    int t = threadIdx.x;
    p[t] = (t < NSCB) ? bsum[t] : 0;
    __syncthreads();
    for (int off = 1; off < 256; off <<= 1) {
        int v = (t >= off) ? p[t - off] : 0;
        __syncthreads();
        p[t] += v;
        __syncthreads();
    }
    if (t < NSCB) boff[t] = (t == 0) ? 0 : p[t - 1];
}

__global__ __launch_bounds__(SCB)
void scan_final_kernel(const int* __restrict__ deg, const int* __restrict__ boff,
                       int* __restrict__ row_start, int* __restrict__ cursor) {
    __shared__ int p[SCB];
    int t = threadIdx.x;
    int i = blockIdx.x * SCB + t;
    int v = (i < NNODES) ? deg[i] : 0;
    p[t] = v;
    __syncthreads();
    for (int off = 1; off < SCB; off <<= 1) {
        int u = (t >= off) ? p[t - off] : 0;
        __syncthreads();
        p[t] += u;
        __syncthreads();
    }
    int excl = boff[blockIdx.x] + p[t] - v;
    if (i < NNODES) {
        row_start[i] = excl;
        cursor[i] = excl;
    }
    if (blockIdx.x == 0 && t == 0) row_start[NNODES] = NEDGES;
}

__global__ __launch_bounds__(256)
void fill_kernel(const int* __restrict__ src, const int* __restrict__ dst,
                 int* __restrict__ cursor, int* __restrict__ e_src, int nE) {
    int e = blockIdx.x * 256 + threadIdx.x;
    if (e < nE) {
        int pos = atomicAdd(&cursor[dst[e]], 1);
        e_src[pos] = src[e];
    }
}

// ---------------- graph segment starts (batch sorted) ----------------
__global__ __launch_bounds__(256)
void gstart_kernel(const int* __restrict__ batch, int* __restrict__ gstart) {
    int g = blockIdx.x * 256 + threadIdx.x;
    if (g > NGRAPH) return;
    if (g == NGRAPH) { gstart[g] = NNODES; return; }
    int lo = 0, hi = NNODES;
    while (lo < hi) { int mid = (lo + hi) >> 1; if (batch[mid] < g) lo = mid + 1; else hi = mid; }
    gstart[g] = lo;
}

// ---------------- weight prep: conv weights -> hi/lo bf16, [L][n][k] ----------------
__global__ __launch_bounds__(256)
void prep_w_kernel(const float* __restrict__ W_rel, const float* __restrict__ W_root,
                   ushort* __restrict__ Wh, ushort* __restrict__ Wl) {
    int i = blockIdx.x * 256 + threadIdx.x;
    if (i >= NLAYERS * D * K2) return;
    int L = i / (D * K2);
    int rem = i % (D * K2);
    int n = rem / K2;
    int k = rem % K2;
    float v = (k < D) ? W_rel[(size_t)L * D * D + (size_t)k * D + n]
                      : W_root[(size_t)L * D * D + (size_t)(k - D) * D + n];
    ushort hi = f2bf(v);
    float  lo = v - bf2f(hi);
    Wh[i] = hi;
    Wl[i] = f2bf(lo);
}

// ---------------- W1 prep: [256 k][1024 n] f32 -> hi/lo bf16 [1024 n][256 k] ----------------
__global__ __launch_bounds__(256)
void prep_w1_kernel(const float* __restrict__ W1,
                    ushort* __restrict__ W1h, ushort* __restrict__ W1l) {
    int i = blockIdx.x * 256 + threadIdx.x;
    if (i >= 1024 * D) return;
    int n = i >> 8;            // 0..1023
    int k = i & (D - 1);       // 0..255
    float v = W1[(size_t)k * 1024 + n];
    ushort hi = f2bf(v);
    W1h[i] = hi;
    W1l[i] = f2bf(v - bf2f(hi));
}

// ---------------- f32 gather-sum: fully predicated 4-wide batches ----------------
__global__ __launch_bounds__(256)
void gather_f32_kernel(const float* __restrict__ x,
                       const int* __restrict__ row_start,
                       const int* __restrict__ e_src,
                       float* __restrict__ aggr) {
    int t = threadIdx.x;
    int n = blockIdx.x * 4 + (t >> 6);
    if (n >= NNODES) return;
    int lane = t & 63;
    int beg = row_start[n], end = row_start[n + 1];
    float a0 = 0.f, a1 = 0.f, a2 = 0.f, a3 = 0.f;
    int e1 = end - 1;
    for (int j = beg; j < end; j += 4) {
        // clamped indices keep 4 loads outstanding even on the tail batch
        int i1 = (j + 1 < end) ? j + 1 : e1;
        int i2 = (j + 2 < end) ? j + 2 : e1;
        int i3 = (j + 3 < end) ? j + 3 : e1;
        int s0 = e_src[j], s1 = e_src[i1], s2 = e_src[i2], s3 = e_src[i3];
        float4 v0 = *reinterpret_cast<const float4*>(x + (size_t)s0 * D + lane * 4);
        float4 v1 = *reinterpret_cast<const float4*>(x + (size_t)s1 * D + lane * 4);
        float4 v2 = *reinterpret_cast<const float4*>(x + (size_t)s2 * D + lane * 4);
        float4 v3 = *reinterpret_cast<const float4*>(x + (size_t)s3 * D + lane * 4);
        float m1 = (j + 1 < end) ? 1.f : 0.f;
        float m2 = (j + 2 < end) ? 1.f : 0.f;
        float m3 = (j + 3 < end) ? 1.f : 0.f;
        a0 += v0.x + m1 * v1.x + m2 * v2.x + m3 * v3.x;
        a1 += v0.y + m1 * v1.y + m2 * v2.y + m3 * v3.y;
        a2 += v0.z + m1 * v1.z + m2 * v2.z + m3 * v3.z;
        a3 += v0.w + m1 * v1.w + m2 * v2.w + m3 * v3.w;
    }
    float4 o; o.x = a0; o.y = a1; o.z = a2; o.w = a3;
    *reinterpret_cast<float4*>(aggr + (size_t)n * D + lane * 4) = o;
}

// ---------------- split-bf16 MFMA GEMM: out = relu([A|X]@W^T + bias), f32 in/out ----------------
// GBM=32 tile: 3128 blocks (12.2/CU), wave-capped 8 blocks/CU = 100% static occupancy.
// 4 waves, each 32 rows x 32 cols (acc[2][2]); LDS 20 KB.
#define GBM 32
#define GBN 128
#define GBK 32

__global__ __launch_bounds__(256)
void gemm_split_kernel(const float* __restrict__ A,
                       const float* __restrict__ X,
                       const ushort* __restrict__ Wh,
                       const ushort* __restrict__ Wl,
                       const float* __restrict__ bias,
                       float* __restrict__ out) {
    __shared__ ushort Ah[GBM * GBK];   // 2 KB
    __shared__ ushort Al[GBM * GBK];   // 2 KB
    __shared__ ushort Bh[GBN * GBK];   // 8 KB
    __shared__ ushort Bl[GBN * GBK];   // 8 KB

    int t = threadIdx.x;
    int w = t >> 6, lane = t & 63;
    int m0 = blockIdx.x * GBM;
    int n0 = blockIdx.y * GBN;
    int r = lane & 15, kq = lane >> 4;

    f32x4 acc[2][2];
#pragma unroll
    for (int m = 0; m < 2; ++m)
#pragma unroll
        for (int n = 0; n < 2; ++n)
            acc[m][n] = (f32x4){0.f, 0.f, 0.f, 0.f};

    // A staging: threads 0..127 own (row t>>2, chunk t&3)
    int arow = t >> 2;
    int acb  = t & 3;
    int ap   = ((arow >> 1) & 3) ^ acb;
    int gr   = m0 + arow;
    bool a_ok = (t < 128) && (gr < NNODES);
    bool a_th = (t < 128);

    for (int k0 = 0; k0 < K2; k0 += GBK) {
        const float* Asrc = (k0 < D) ? A : X;
        int kk = k0 & (D - 1);

        // ---- B staging: global_load_lds, pre-swizzled source
#pragma unroll
        for (int op = 0; op < 2; ++op) {
            int idx = op * 256 + t;
            int row = idx >> 2, sub = idx & 3;
            int kh = ((row >> 1) & 3) ^ sub;
            stage16(Wh + (size_t)(n0 + row) * K2 + k0 + kh * 8, Bh + (size_t)idx * 8);
            stage16(Wl + (size_t)(n0 + row) * K2 + k0 + kh * 8, Bl + (size_t)idx * 8);
        }

        // ---- A staging: 8 f32 -> hi/lo bf16 -> swizzled ds_write (threads < 128)
        if (a_th) {
            const float* base = Asrc + (size_t)gr * D + kk + acb * 8;
            float4 v0, v1;
            if (a_ok) {
                v0 = *reinterpret_cast<const float4*>(base + 0);
                v1 = *reinterpret_cast<const float4*>(base + 4);
            } else {
                v0 = v1 = make_float4(0.f, 0.f, 0.f, 0.f);
            }
            float vv[8] = {v0.x, v0.y, v0.z, v0.w, v1.x, v1.y, v1.z, v1.w};
            ushort hi[8], lo[8];
#pragma unroll
            for (int i = 0; i < 8; ++i) {
                hi[i] = f2bf(vv[i]);
                lo[i] = f2bf(vv[i] - bf2f(hi[i]));
            }
            *reinterpret_cast<uint4*>(&Ah[arow * GBK + ap * 8]) = *reinterpret_cast<const uint4*>(hi);
            *reinterpret_cast<uint4*>(&Al[arow * GBK + ap * 8]) = *reinterpret_cast<const uint4*>(lo);
        }
        __syncthreads();

        // ---- fragment reads (swizzle-matched)
        bf16x8 ah[2], al[2], bh[2], bl[2];
#pragma unroll
        for (int m = 0; m < 2; ++m) {
            int row = m * 16 + r;
            int off = row * GBK + ((((row >> 1) & 3) ^ kq) * 8);
            ah[m] = *reinterpret_cast<const bf16x8*>(&Ah[off]);
            al[m] = *reinterpret_cast<const bf16x8*>(&Al[off]);
        }
#pragma unroll
        for (int n = 0; n < 2; ++n) {
            int row = w * 32 + n * 16 + r;
            int off = row * GBK + ((((row >> 1) & 3) ^ kq) * 8);
            bh[n] = *reinterpret_cast<const bf16x8*>(&Bh[off]);
            bl[n] = *reinterpret_cast<const bf16x8*>(&Bl[off]);
        }
        __syncthreads();   // fragments in VGPRs; LDS free for next stage

        // ---- 12 MFMA
#pragma unroll
        for (int m = 0; m < 2; ++m)
#pragma unroll
            for (int n = 0; n < 2; ++n) {
                acc[m][n] = __builtin_amdgcn_mfma_f32_16x16x32_bf16(ah[m], bh[n], acc[m][n], 0, 0, 0);
                acc[m][n] = __builtin_amdgcn_mfma_f32_16x16x32_bf16(ah[m], bl[n], acc[m][n], 0, 0, 0);
                acc[m][n] = __builtin_amdgcn_mfma_f32_16x16x32_bf16(al[m], bh[n], acc[m][n], 0, 0, 0);
            }
    }

    // ---- epilogue: bias + relu -> f32
#pragma unroll
    for (int n = 0; n < 2; ++n) {
        int col = n0 + w * 32 + n * 16 + r;
        float bv = bias[col];
#pragma unroll
        for (int m = 0; m < 2; ++m) {
            int rbase = m0 + m * 16 + kq * 4;
#pragma unroll
            for (int j = 0; j < 4; ++j) {
                int rr = rbase + j;
                if (rr < NNODES)
                    out[(size_t)rr * D + col] = fmaxf(acc[m][n][j] + bv, 0.f);
            }
        }
    }
}

// ---------------- segmented pool (f32, batch sorted, no atomics) ----------------
__global__ __launch_bounds__(256)
void pool_seg_kernel(const float* __restrict__ x, const int* __restrict__ gstart,
                     float* __restrict__ pooled) {
    __shared__ float red[4][D];
    int g = blockIdx.x;
    int t = threadIdx.x, wid = t >> 6, lane = t & 63;
    int beg = gstart[g], end = gstart[g + 1];
    float a0 = 0.f, a1 = 0.f, a2 = 0.f, a3 = 0.f;
    for (int r = beg + wid; r < end; r += 4) {
        float4 v = *reinterpret_cast<const float4*>(x + (size_t)r * D + lane * 4);
        a0 += v.x; a1 += v.y; a2 += v.z; a3 += v.w;
    }
    red[wid][lane * 4 + 0] = a0;
    red[wid][lane * 4 + 1] = a1;
    red[wid][lane * 4 + 2] = a2;
    red[wid][lane * 4 + 3] = a3;
    __syncthreads();
    float s = red[0][t] + red[1][t] + red[2][t] + red[3][t];
    pooled[(size_t)g * D + t] = s;
}

// ---------------- mlp1 as split-bf16 MFMA GEMM: h = relu(pooled @ W1 + b1) ----------------
// M=512, N=1024, K=256. Tile 32x128, grid (16,8).
__global__ __launch_bounds__(256)
void mlp1_gemm_kernel(const float* __restrict__ P,
                      const ushort* __restrict__ W1h,
                      const ushort* __restrict__ W1l,
                      const float* __restrict__ b1,
                      float* __restrict__ h) {
    __shared__ ushort Ah[GBM * GBK];
    __shared__ ushort Al[GBM * GBK];
    __shared__ ushort Bh[GBN * GBK];
    __shared__ ushort Bl[GBN * GBK];

    int t = threadIdx.x;
    int w = t >> 6, lane = t & 63;
    int m0 = blockIdx.x * GBM;
    int n0 = blockIdx.y * GBN;
    int r = lane & 15, kq = lane >> 4;

    f32x4 acc[2][2];
#pragma unroll
    for (int m = 0; m < 2; ++m)
#pragma unroll
        for (int n = 0; n < 2; ++n)
            acc[m][n] = (f32x4){0.f, 0.f, 0.f, 0.f};

    int arow = t >> 2;
    int acb  = t & 3;
    int ap   = ((arow >> 1) & 3) ^ acb;
    int gr   = m0 + arow;
    bool a_th = (t < 128);

    for (int k0 = 0; k0 < D; k0 += GBK) {   // K = 256 -> 8 steps
#pragma unroll
        for (int op = 0; op < 2; ++op) {
            int idx = op * 256 + t;
            int row = idx >> 2, sub = idx & 3;
            int kh = ((row >> 1) & 3) ^ sub;
            stage16(W1h + (size_t)(n0 + row) * D + k0 + kh * 8, Bh + (size_t)idx * 8);
            stage16(W1l + (size_t)(n0 + row) * D + k0 + kh * 8, Bl + (size_t)idx * 8);
        }
        if (a_th) {
            const float* base = P + (size_t)gr * D + k0 + acb * 8;
            float4 v0 = *reinterpret_cast<const float4*>(base + 0);
            float4 v1 = *reinterpret_cast<const float4*>(base + 4);
            float vv[8] = {v0.x, v0.y, v0.z, v0.w, v1.x, v1.y, v1.z, v1.w};
            ushort hi[8], lo[8];
#pragma unroll
            for (int i = 0; i < 8; ++i) {
                hi[i] = f2bf(vv[i]);
                lo[i] = f2bf(vv[i] - bf2f(hi[i]));
            }
            *reinterpret_cast<uint4*>(&Ah[arow * GBK + ap * 8]) = *reinterpret_cast<const uint4*>(hi);
            *reinterpret_cast<uint4*>(&Al[arow * GBK + ap * 8]) = *reinterpret_cast<const uint4*>(lo);
        }
        __syncthreads();

        bf16x8 ah[2], al[2], bh[2], bl[2];
#pragma unroll
        for (int m = 0; m < 2; ++m) {
            int row = m * 16 + r;
            int off = row * GBK + ((((row >> 1) & 3) ^ kq) * 8);
            ah[m] = *reinterpret_cast<const bf16x8*>(&Ah[off]);
            al[m] = *reinterpret_cast<const bf16x8*>(&Al[off]);
        }
#pragma unroll
        for (int n = 0; n < 2; ++n) {
            int row = w * 32 + n * 16 + r;
            int off = row * GBK + ((((row >> 1) & 3) ^ kq) * 8);
            bh[n] = *reinterpret_cast<const bf16x8*>(&Bh[off]);
            bl[n] = *reinterpret_cast<const bf16x8*>(&Bl[off]);
        }
        __syncthreads();

#pragma unroll
        for (int m = 0; m < 2; ++m)
#pragma unroll
            for (int n = 0; n < 2; ++n) {
                acc[m][n] = __builtin_amdgcn_mfma_f32_16x16x32_bf16(ah[m], bh[n], acc[m][n], 0, 0, 0);
                acc[m][n] = __builtin_amdgcn_mfma_f32_16x16x32_bf16(ah[m], bl[n], acc[m][n], 0, 0, 0);
                acc[m][n] = __builtin_amdgcn_mfma_f32_16x16x32_bf16(al[m], bh[n], acc[m][n], 0, 0, 0);
            }
    }

#pragma unroll
    for (int n = 0; n < 2; ++n) {
        int col = n0 + w * 32 + n * 16 + r;
        float bv = b1[col];
#pragma unroll
        for (int m = 0; m < 2; ++m) {
            int rbase = m0 + m * 16 + kq * 4;
#pragma unroll
            for (int j = 0; j < 4; ++j) {
                int rr = rbase + j;
                h[(size_t)rr * 1024 + col] = fmaxf(acc[m][n][j] + bv, 0.f);
            }
        }
    }
}

// ---------------- MLP layer 2 (f32) ----------------
__global__ __launch_bounds__(256)
void mlp2_kernel(const float* __restrict__ h, const float* __restrict__ W2,
                 const float* __restrict__ b2, float* __restrict__ out) {
    __shared__ float red[8][32];
    int g = blockIdx.x, t = threadIdx.x;
    int c = t & 31, kc = t >> 5;
    float s = 0.f;
    const float* hr = h + (size_t)g * 1024;
#pragma unroll 4
    for (int k = kc * 128; k < kc * 128 + 128; ++k)
        s += hr[k] * W2[(size_t)k * 32 + c];
    red[kc][c] = s;
    __syncthreads();
    if (t < 32) {
        float v = b2[t];
#pragma unroll
        for (int i = 0; i < 8; ++i) v += red[i][t];
        out[(size_t)g * 32 + t] = 1.f / (1.f + expf(-v));
    }
}

extern "C" void kernel_launch(void* const* d_in, const int* in_sizes, int n_in,
                              void* d_out, int out_size, void* d_ws, size_t ws_size,
                              hipStream_t stream) {
    const float* x      = (const float*)d_in[0];
    const int*   ei     = (const int*)d_in[1];
    const int*   batch  = (const int*)d_in[2];
    const float* W_rel  = (const float*)d_in[3];
    const float* W_root = (const float*)d_in[4];
    const float* b_conv = (const float*)d_in[5];
    const float* W1     = (const float*)d_in[6];
    const float* b1     = (const float*)d_in[7];
    const float* W2     = (const float*)d_in[8];
    const float* b2     = (const float*)d_in[9];
    float* outp = (float*)d_out;

    const size_t NF = (size_t)MPAD * D;
    float* aggr   = (float*)d_ws;            // [MPAD][256]
    float* buf0   = aggr + NF;
    float* buf1   = buf0 + NF;
    ushort* Wh    = (ushort*)(buf1 + NF);    // 3*256*512 each
    ushort* Wl    = Wh + (size_t)NLAYERS * D * K2;
    ushort* W1h   = Wl + (size_t)NLAYERS * D * K2;   // 1024*256 each
    ushort* W1l   = W1h + (size_t)1024 * D;
    float* pooled = (float*)(W1l + (size_t)1024 * D);   // [512][256]
    float* hbuf   = pooled + (size_t)NGRAPH * D;        // [512][1024]
    int* deg       = (int*)(hbuf + (size_t)NGRAPH * 1024);
    int* row_start = deg + NNODES;           // NNODES+1
    int* cursor    = row_start + NNODES + 1;
    int* e_src     = cursor + NNODES;        // NEDGES
    int* gstart    = e_src + NEDGES;         // NGRAPH+1
    int* bsum      = gstart + NGRAPH + 1;    // NSCB
    int* boff      = bsum + NSCB;            // NSCB

    const int* srcp = ei;
    const int* dstp = ei + NEDGES;

    // CSR build (reused by all layers) — multi-block scan
    hipMemsetAsync(deg, 0, NNODES * sizeof(int), stream);
    hist_kernel<<<(NEDGES + 255) / 256, 256, 0, stream>>>(dstp, deg, NEDGES);
    scan_part_kernel<<<NSCB, SCB, 0, stream>>>(deg, bsum);
    scan_bsum_kernel<<<1, 256, 0, stream>>>(bsum, boff);
    scan_final_kernel<<<NSCB, SCB, 0, stream>>>(deg, boff, row_start, cursor);
    fill_kernel<<<(NEDGES + 255) / 256, 256, 0, stream>>>(srcp, dstp, cursor, e_src, NEDGES);
    gstart_kernel<<<3, 256, 0, stream>>>(batch, gstart);

    prep_w_kernel<<<(NLAYERS * D * K2 + 255) / 256, 256, 0, stream>>>(W_rel, W_root, Wh, Wl);
    prep_w1_kernel<<<(1024 * D + 255) / 256, 256, 0, stream>>>(W1, W1h, W1l);

    int gatherBlocks = (NNODES + 3) / 4;
    dim3 ggrid(MPAD / GBM, D / GBN);

    const float* cur = x;
    float* nxt = buf0;
    for (int L = 0; L < NLAYERS; ++L) {
        gather_f32_kernel<<<gatherBlocks, 256, 0, stream>>>(cur, row_start, e_src, aggr);
        gemm_split_kernel<<<ggrid, 256, 0, stream>>>(aggr, cur,
                                                     Wh + (size_t)L * D * K2,
                                                     Wl + (size_t)L * D * K2,
                                                     b_conv + (size_t)L * D,
                                                     nxt);
        cur = nxt;
        nxt = (nxt == buf0) ? buf1 : buf0;
    }

    pool_seg_kernel<<<NGRAPH, 256, 0, stream>>>(cur, gstart, pooled);
    mlp1_gemm_kernel<<<dim3(NGRAPH / GBM, 1024 / GBN), 256, 0, stream>>>(pooled, W1h, W1l, b1, hbuf);
    mlp2_kernel<<<NGRAPH, 256, 0, stream>>>(hbuf, W2, b2, outp);
}

// Round 16
// 409.886 us; speedup vs baseline: 1.1315x; 1.1315x over previous
//
#include <hip/hip_runtime.h>
#include <math.h>

#define NNODES 50000
#define MPAD   50048    // NNODES rounded up to 128
#define D      256
#define K2     512
#define NEDGES 300000
#define NGRAPH 512
#define NLAYERS 3

#define SCB    256
#define NSCB   ((NNODES + SCB - 1) / SCB)   // 196 blocks

typedef __bf16 bf16x8 __attribute__((ext_vector_type(8)));
typedef float  f32x4  __attribute__((ext_vector_type(4)));

__device__ __forceinline__ ushort f2bf(float f) {
    unsigned u = __float_as_uint(f);
    unsigned r = (u + 0x7FFFu + ((u >> 16) & 1u)) >> 16;   // RNE
    return (ushort)r;
}
__device__ __forceinline__ float bf2f(ushort b) {
    return __uint_as_float(((unsigned)b) << 16);
}

__device__ __forceinline__ void stage16(const ushort* g, ushort* l) {
    __builtin_amdgcn_global_load_lds(
        (const __attribute__((address_space(1))) unsigned*)g,
        (__attribute__((address_space(3))) unsigned*)l, 16, 0, 0);
}

// ---------------- CSR build ----------------
__global__ __launch_bounds__(256)
void hist_kernel(const int* __restrict__ dst, int* __restrict__ deg, int nE) {
    int e = blockIdx.x * 256 + threadIdx.x;
    if (e < nE) atomicAdd(&deg[dst[e]], 1);
}

__global__ __launch_bounds__(SCB)
void scan_part_kernel(const int* __restrict__ deg, int* __restrict__ bsum) {
    __shared__ int red[SCB];
    int t = threadIdx.x;
    int i = blockIdx.x * SCB + t;
    red[t] = (i < NNODES) ? deg[i] : 0;
    __syncthreads();
#pragma unroll
    for (int off = SCB / 2; off > 0; off >>= 1) {
        if (t < off) red[t] += red[t + off];
        __syncthreads();
    }
    if (t == 0) bsum[blockIdx.x] = red[0];
}

__global__ __launch_bounds__(256)
void scan_bsum_kernel(const int* __restrict__ bsum, int* __restrict__ boff) {
    __shared__ int p[256];
    int t = threadIdx.x;
    p[t] = (t < NSCB) ? bsum[t] : 0;
    __syncthreads();
    for (int off = 1; off < 256; off <<= 1) {
        int v = (t >= off) ? p[t - off] : 0;
        __syncthreads();
        p[t] += v;
        __syncthreads();
    }
    if (t < NSCB) boff[t] = (t == 0) ? 0 : p[t - 1];
}

__global__ __launch_bounds__(SCB)
void scan_final_kernel(const int* __restrict__ deg, const int* __restrict__ boff,
                       int* __restrict__ row_start, int* __restrict__ cursor) {
    __shared__ int p[SCB];
    int t = threadIdx.x;
    int i = blockIdx.x * SCB + t;
    int v = (i < NNODES) ? deg[i] : 0;
    p[t] = v;
    __syncthreads();
    for (int off = 1; off < SCB; off <<= 1) {
        int u = (t >= off) ? p[t - off] : 0;
        __syncthreads();
        p[t] += u;
        __syncthreads();
    }
    int excl = boff[blockIdx.x] + p[t] - v;
    if (i < NNODES) {
        row_start[i] = excl;
        cursor[i] = excl;
    }
    if (blockIdx.x == 0 && t == 0) row_start[NNODES] = NEDGES;
}

__global__ __launch_bounds__(256)
void fill_kernel(const int* __restrict__ src, const int* __restrict__ dst,
                 int* __restrict__ cursor, int* __restrict__ e_src, int nE) {
    int e = blockIdx.x * 256 + threadIdx.x;
    if (e < nE) {
        int pos = atomicAdd(&cursor[dst[e]], 1);
        e_src[pos] = src[e];
    }
}

// ---------------- graph segment starts (batch sorted) ----------------
__global__ __launch_bounds__(256)
void gstart_kernel(const int* __restrict__ batch, int* __restrict__ gstart) {
    int g = blockIdx.x * 256 + threadIdx.x;
    if (g > NGRAPH) return;
    if (g == NGRAPH) { gstart[g] = NNODES; return; }
    int lo = 0, hi = NNODES;
    while (lo < hi) { int mid = (lo + hi) >> 1; if (batch[mid] < g) lo = mid + 1; else hi = mid; }
    gstart[g] = lo;
}

// ---------------- weight prep: conv weights -> hi/lo bf16, [L][n][k] ----------------
__global__ __launch_bounds__(256)
void prep_w_kernel(const float* __restrict__ W_rel, const float* __restrict__ W_root,
                   ushort* __restrict__ Wh, ushort* __restrict__ Wl) {
    int i = blockIdx.x * 256 + threadIdx.x;
    if (i >= NLAYERS * D * K2) return;
    int L = i / (D * K2);
    int rem = i % (D * K2);
    int n = rem / K2;
    int k = rem % K2;
    float v = (k < D) ? W_rel[(size_t)L * D * D + (size_t)k * D + n]
                      : W_root[(size_t)L * D * D + (size_t)(k - D) * D + n];
    ushort hi = f2bf(v);
    float  lo = v - bf2f(hi);
    Wh[i] = hi;
    Wl[i] = f2bf(lo);
}

// ---------------- W1 prep: [256 k][1024 n] f32 -> hi/lo bf16 [1024 n][256 k] ----------------
__global__ __launch_bounds__(256)
void prep_w1_kernel(const float* __restrict__ W1,
                    ushort* __restrict__ W1h, ushort* __restrict__ W1l) {
    int i = blockIdx.x * 256 + threadIdx.x;
    if (i >= 1024 * D) return;
    int n = i >> 8;            // 0..1023
    int k = i & (D - 1);       // 0..255
    float v = W1[(size_t)k * 1024 + n];
    ushort hi = f2bf(v);
    W1h[i] = hi;
    W1l[i] = f2bf(v - bf2f(hi));
}

// ---------------- f32 gather-sum with 4-wide index unroll ----------------
__global__ __launch_bounds__(256)
void gather_f32_kernel(const float* __restrict__ x,
                       const int* __restrict__ row_start,
                       const int* __restrict__ e_src,
                       float* __restrict__ aggr) {
    int t = threadIdx.x;
    int n = blockIdx.x * 4 + (t >> 6);
    if (n >= NNODES) return;
    int lane = t & 63;
    int beg = row_start[n], end = row_start[n + 1];
    float a0 = 0.f, a1 = 0.f, a2 = 0.f, a3 = 0.f;
    int j = beg;
    for (; j + 4 <= end; j += 4) {
        int s0 = e_src[j], s1 = e_src[j + 1], s2 = e_src[j + 2], s3 = e_src[j + 3];
        float4 v0 = *reinterpret_cast<const float4*>(x + (size_t)s0 * D + lane * 4);
        float4 v1 = *reinterpret_cast<const float4*>(x + (size_t)s1 * D + lane * 4);
        float4 v2 = *reinterpret_cast<const float4*>(x + (size_t)s2 * D + lane * 4);
        float4 v3 = *reinterpret_cast<const float4*>(x + (size_t)s3 * D + lane * 4);
        a0 += v0.x + v1.x + v2.x + v3.x;
        a1 += v0.y + v1.y + v2.y + v3.y;
        a2 += v0.z + v1.z + v2.z + v3.z;
        a3 += v0.w + v1.w + v2.w + v3.w;
    }
    for (; j < end; ++j) {
        int s = e_src[j];
        float4 v = *reinterpret_cast<const float4*>(x + (size_t)s * D + lane * 4);
        a0 += v.x; a1 += v.y; a2 += v.z; a3 += v.w;
    }
    float4 o; o.x = a0; o.y = a1; o.z = a2; o.w = a3;
    *reinterpret_cast<float4*>(aggr + (size_t)n * D + lane * 4) = o;
}

// ---------------- split-bf16 MFMA GEMM: out = relu([A|X]@W^T + bias), f32 in/out ----------------
// GBM=64 tile: 1564 blocks (6.1/CU). Measured tile curve: 79.5us@128, 68us@64, 85us@32.
#define GBM 64
#define GBN 128
#define GBK 32

__global__ __launch_bounds__(256)
void gemm_split_kernel(const float* __restrict__ A,
                       const float* __restrict__ X,
                       const ushort* __restrict__ Wh,
                       const ushort* __restrict__ Wl,
                       const float* __restrict__ bias,
                       float* __restrict__ out) {
    __shared__ ushort Ah[GBM * GBK];   // 4 KB
    __shared__ ushort Al[GBM * GBK];   // 4 KB
    __shared__ ushort Bh[GBN * GBK];   // 8 KB
    __shared__ ushort Bl[GBN * GBK];   // 8 KB

    int t = threadIdx.x;
    int wid = t >> 6, lane = t & 63;
    int m0 = blockIdx.x * GBM;
    int n0 = blockIdx.y * GBN;
    int wr = wid >> 1, wc = wid & 1;   // wave tile: 32 rows x 64 cols
    int r = lane & 15, kq = lane >> 4;

    f32x4 acc[2][4];
#pragma unroll
    for (int m = 0; m < 2; ++m)
#pragma unroll
        for (int n = 0; n < 4; ++n)
            acc[m][n] = (f32x4){0.f, 0.f, 0.f, 0.f};

    // A staging: thread t owns row t>>2, one 8-elem k-chunk (t&3)
    int arow = t >> 2;
    int acb  = t & 3;
    int ap   = ((arow >> 1) & 3) ^ acb;     // swizzled physical chunk
    int gr   = m0 + arow;
    bool arow_ok = (gr < NNODES);

    for (int k0 = 0; k0 < K2; k0 += GBK) {
        const float* Asrc = (k0 < D) ? A : X;
        int kk = k0 & (D - 1);

        // ---- B staging: global_load_lds, pre-swizzled source
#pragma unroll
        for (int op = 0; op < 2; ++op) {
            int idx = op * 256 + t;
            int row = idx >> 2, sub = idx & 3;
            int kh = ((row >> 1) & 3) ^ sub;
            stage16(Wh + (size_t)(n0 + row) * K2 + k0 + kh * 8, Bh + (size_t)idx * 8);
            stage16(Wl + (size_t)(n0 + row) * K2 + k0 + kh * 8, Bl + (size_t)idx * 8);
        }

        // ---- A staging: 8 f32 -> hi/lo bf16 -> swizzled ds_write_b128
        {
            const float* base = Asrc + (size_t)gr * D + kk + acb * 8;
            float4 v0, v1;
            if (arow_ok) {
                v0 = *reinterpret_cast<const float4*>(base + 0);
                v1 = *reinterpret_cast<const float4*>(base + 4);
            } else {
                v0 = v1 = make_float4(0.f, 0.f, 0.f, 0.f);
            }
            float vv[8] = {v0.x, v0.y, v0.z, v0.w, v1.x, v1.y, v1.z, v1.w};
            ushort hi[8], lo[8];
#pragma unroll
            for (int i = 0; i < 8; ++i) {
                hi[i] = f2bf(vv[i]);
                lo[i] = f2bf(vv[i] - bf2f(hi[i]));
            }
            *reinterpret_cast<uint4*>(&Ah[arow * GBK + ap * 8]) = *reinterpret_cast<const uint4*>(hi);
            *reinterpret_cast<uint4*>(&Al[arow * GBK + ap * 8]) = *reinterpret_cast<const uint4*>(lo);
        }
        __syncthreads();

        // ---- fragment reads (swizzle-matched)
        bf16x8 ah[2], al[2], bh[4], bl[4];
#pragma unroll
        for (int m = 0; m < 2; ++m) {
            int row = wr * 32 + m * 16 + r;
            int off = row * GBK + ((((row >> 1) & 3) ^ kq) * 8);
            ah[m] = *reinterpret_cast<const bf16x8*>(&Ah[off]);
            al[m] = *reinterpret_cast<const bf16x8*>(&Al[off]);
        }
#pragma unroll
        for (int n = 0; n < 4; ++n) {
            int row = wc * 64 + n * 16 + r;
            int off = row * GBK + ((((row >> 1) & 3) ^ kq) * 8);
            bh[n] = *reinterpret_cast<const bf16x8*>(&Bh[off]);
            bl[n] = *reinterpret_cast<const bf16x8*>(&Bl[off]);
        }
        __syncthreads();   // fragments in VGPRs; LDS free for next stage

        // ---- 24 MFMA (runs while other waves stage the next tile)
#pragma unroll
        for (int m = 0; m < 2; ++m)
#pragma unroll
            for (int n = 0; n < 4; ++n) {
                acc[m][n] = __builtin_amdgcn_mfma_f32_16x16x32_bf16(ah[m], bh[n], acc[m][n], 0, 0, 0);
                acc[m][n] = __builtin_amdgcn_mfma_f32_16x16x32_bf16(ah[m], bl[n], acc[m][n], 0, 0, 0);
                acc[m][n] = __builtin_amdgcn_mfma_f32_16x16x32_bf16(al[m], bh[n], acc[m][n], 0, 0, 0);
            }
    }

    // ---- epilogue: bias + relu -> f32
#pragma unroll
    for (int n = 0; n < 4; ++n) {
        int col = n0 + wc * 64 + n * 16 + r;
        float bv = bias[col];
#pragma unroll
        for (int m = 0; m < 2; ++m) {
            int rbase = m0 + wr * 32 + m * 16 + kq * 4;
#pragma unroll
            for (int j = 0; j < 4; ++j) {
                int rr = rbase + j;
                if (rr < NNODES)
                    out[(size_t)rr * D + col] = fmaxf(acc[m][n][j] + bv, 0.f);
            }
        }
    }
}

// ---------------- segmented pool (f32, batch sorted, no atomics) ----------------
__global__ __launch_bounds__(256)
void pool_seg_kernel(const float* __restrict__ x, const int* __restrict__ gstart,
                     float* __restrict__ pooled) {
    __shared__ float red[4][D];
    int g = blockIdx.x;
    int t = threadIdx.x, wid = t >> 6, lane = t & 63;
    int beg = gstart[g], end = gstart[g + 1];
    float a0 = 0.f, a1 = 0.f, a2 = 0.f, a3 = 0.f;
    for (int r = beg + wid; r < end; r += 4) {
        float4 v = *reinterpret_cast<const float4*>(x + (size_t)r * D + lane * 4);
        a0 += v.x; a1 += v.y; a2 += v.z; a3 += v.w;
    }
    red[wid][lane * 4 + 0] = a0;
    red[wid][lane * 4 + 1] = a1;
    red[wid][lane * 4 + 2] = a2;
    red[wid][lane * 4 + 3] = a3;
    __syncthreads();
    float s = red[0][t] + red[1][t] + red[2][t] + red[3][t];
    pooled[(size_t)g * D + t] = s;
}

// ---------------- mlp1 as split-bf16 MFMA GEMM: h = relu(pooled @ W1 + b1) ----------------
// M=512 (graphs), N=1024, K=256. Tile 64x128, grid (8,8). All rows valid.
__global__ __launch_bounds__(256)
void mlp1_gemm_kernel(const float* __restrict__ P,
                      const ushort* __restrict__ W1h,
                      const ushort* __restrict__ W1l,
                      const float* __restrict__ b1,
                      float* __restrict__ h) {
    __shared__ ushort Ah[GBM * GBK];
    __shared__ ushort Al[GBM * GBK];
    __shared__ ushort Bh[GBN * GBK];
    __shared__ ushort Bl[GBN * GBK];

    int t = threadIdx.x;
    int wid = t >> 6, lane = t & 63;
    int m0 = blockIdx.x * GBM;
    int n0 = blockIdx.y * GBN;
    int wr = wid >> 1, wc = wid & 1;
    int r = lane & 15, kq = lane >> 4;

    f32x4 acc[2][4];
#pragma unroll
    for (int m = 0; m < 2; ++m)
#pragma unroll
        for (int n = 0; n < 4; ++n)
            acc[m][n] = (f32x4){0.f, 0.f, 0.f, 0.f};

    int arow = t >> 2;
    int acb  = t & 3;
    int ap   = ((arow >> 1) & 3) ^ acb;
    int gr   = m0 + arow;                   // < 512 always

    for (int k0 = 0; k0 < D; k0 += GBK) {   // K = 256 -> 8 steps
        // B staging (W1 hi/lo, [n][k] layout, stride D)
#pragma unroll
        for (int op = 0; op < 2; ++op) {
            int idx = op * 256 + t;
            int row = idx >> 2, sub = idx & 3;
            int kh = ((row >> 1) & 3) ^ sub;
            stage16(W1h + (size_t)(n0 + row) * D + k0 + kh * 8, Bh + (size_t)idx * 8);
            stage16(W1l + (size_t)(n0 + row) * D + k0 + kh * 8, Bl + (size_t)idx * 8);
        }
        // A staging (pooled f32 -> hi/lo)
        {
            const float* base = P + (size_t)gr * D + k0 + acb * 8;
            float4 v0 = *reinterpret_cast<const float4*>(base + 0);
            float4 v1 = *reinterpret_cast<const float4*>(base + 4);
            float vv[8] = {v0.x, v0.y, v0.z, v0.w, v1.x, v1.y, v1.z, v1.w};
            ushort hi[8], lo[8];
#pragma unroll
            for (int i = 0; i < 8; ++i) {
                hi[i] = f2bf(vv[i]);
                lo[i] = f2bf(vv[i] - bf2f(hi[i]));
            }
            *reinterpret_cast<uint4*>(&Ah[arow * GBK + ap * 8]) = *reinterpret_cast<const uint4*>(hi);
            *reinterpret_cast<uint4*>(&Al[arow * GBK + ap * 8]) = *reinterpret_cast<const uint4*>(lo);
        }
        __syncthreads();

        bf16x8 ah[2], al[2], bh[4], bl[4];
#pragma unroll
        for (int m = 0; m < 2; ++m) {
            int row = wr * 32 + m * 16 + r;
            int off = row * GBK + ((((row >> 1) & 3) ^ kq) * 8);
            ah[m] = *reinterpret_cast<const bf16x8*>(&Ah[off]);
            al[m] = *reinterpret_cast<const bf16x8*>(&Al[off]);
        }
#pragma unroll
        for (int n = 0; n < 4; ++n) {
            int row = wc * 64 + n * 16 + r;
            int off = row * GBK + ((((row >> 1) & 3) ^ kq) * 8);
            bh[n] = *reinterpret_cast<const bf16x8*>(&Bh[off]);
            bl[n] = *reinterpret_cast<const bf16x8*>(&Bl[off]);
        }
        __syncthreads();

#pragma unroll
        for (int m = 0; m < 2; ++m)
#pragma unroll
            for (int n = 0; n < 4; ++n) {
                acc[m][n] = __builtin_amdgcn_mfma_f32_16x16x32_bf16(ah[m], bh[n], acc[m][n], 0, 0, 0);
                acc[m][n] = __builtin_amdgcn_mfma_f32_16x16x32_bf16(ah[m], bl[n], acc[m][n], 0, 0, 0);
                acc[m][n] = __builtin_amdgcn_mfma_f32_16x16x32_bf16(al[m], bh[n], acc[m][n], 0, 0, 0);
            }
    }

    // epilogue: bias + relu -> h [512][1024]
#pragma unroll
    for (int n = 0; n < 4; ++n) {
        int col = n0 + wc * 64 + n * 16 + r;
        float bv = b1[col];
#pragma unroll
        for (int m = 0; m < 2; ++m) {
            int rbase = m0 + wr * 32 + m * 16 + kq * 4;
#pragma unroll
            for (int j = 0; j < 4; ++j) {
                int rr = rbase + j;
                h[(size_t)rr * 1024 + col] = fmaxf(acc[m][n][j] + bv, 0.f);
            }
        }
    }
}

// ---------------- MLP layer 2 (f32) ----------------
__global__ __launch_bounds__(256)
void mlp2_kernel(const float* __restrict__ h, const float* __restrict__ W2,
                 const float* __restrict__ b2, float* __restrict__ out) {
    __shared__ float red[8][32];
    int g = blockIdx.x, t = threadIdx.x;
    int c = t & 31, kc = t >> 5;
    float s = 0.f;
    const float* hr = h + (size_t)g * 1024;
#pragma unroll 4
    for (int k = kc * 128; k < kc * 128 + 128; ++k)
        s += hr[k] * W2[(size_t)k * 32 + c];
    red[kc][c] = s;
    __syncthreads();
    if (t < 32) {
        float v = b2[t];
#pragma unroll
        for (int i = 0; i < 8; ++i) v += red[i][t];
        out[(size_t)g * 32 + t] = 1.f / (1.f + expf(-v));
    }
}

extern "C" void kernel_launch(void* const* d_in, const int* in_sizes, int n_in,
                              void* d_out, int out_size, void* d_ws, size_t ws_size,
                              hipStream_t stream) {
    const float* x      = (const float*)d_in[0];
    const int*   ei     = (const int*)d_in[1];
    const int*   batch  = (const int*)d_in[2];
    const float* W_rel  = (const float*)d_in[3];
    const float* W_root = (const float*)d_in[4];
    const float* b_conv = (const float*)d_in[5];
    const float* W1     = (const float*)d_in[6];
    const float* b1     = (const float*)d_in[7];
    const float* W2     = (const float*)d_in[8];
    const float* b2     = (const float*)d_in[9];
    float* outp = (float*)d_out;

    const size_t NF = (size_t)MPAD * D;
    float* aggr   = (float*)d_ws;            // [MPAD][256]
    float* buf0   = aggr + NF;
    float* buf1   = buf0 + NF;
    ushort* Wh    = (ushort*)(buf1 + NF);    // 3*256*512 each
    ushort* Wl    = Wh + (size_t)NLAYERS * D * K2;
    ushort* W1h   = Wl + (size_t)NLAYERS * D * K2;   // 1024*256 each
    ushort* W1l   = W1h + (size_t)1024 * D;
    float* pooled = (float*)(W1l + (size_t)1024 * D);   // [512][256]
    float* hbuf   = pooled + (size_t)NGRAPH * D;        // [512][1024]
    int* deg       = (int*)(hbuf + (size_t)NGRAPH * 1024);
    int* row_start = deg + NNODES;           // NNODES+1
    int* cursor    = row_start + NNODES + 1;
    int* e_src     = cursor + NNODES;        // NEDGES
    int* gstart    = e_src + NEDGES;         // NGRAPH+1
    int* bsum      = gstart + NGRAPH + 1;    // NSCB
    int* boff      = bsum + NSCB;            // NSCB

    const int* srcp = ei;
    const int* dstp = ei + NEDGES;

    // CSR build (reused by all layers) — multi-block scan
    hipMemsetAsync(deg, 0, NNODES * sizeof(int), stream);
    hist_kernel<<<(NEDGES + 255) / 256, 256, 0, stream>>>(dstp, deg, NEDGES);
    scan_part_kernel<<<NSCB, SCB, 0, stream>>>(deg, bsum);
    scan_bsum_kernel<<<1, 256, 0, stream>>>(bsum, boff);
    scan_final_kernel<<<NSCB, SCB, 0, stream>>>(deg, boff, row_start, cursor);
    fill_kernel<<<(NEDGES + 255) / 256, 256, 0, stream>>>(srcp, dstp, cursor, e_src, NEDGES);
    gstart_kernel<<<3, 256, 0, stream>>>(batch, gstart);

    prep_w_kernel<<<(NLAYERS * D * K2 + 255) / 256, 256, 0, stream>>>(W_rel, W_root, Wh, Wl);
    prep_w1_kernel<<<(1024 * D + 255) / 256, 256, 0, stream>>>(W1, W1h, W1l);

    int gatherBlocks = (NNODES + 3) / 4;
    dim3 ggrid(MPAD / GBM, D / GBN);

    const float* cur = x;
    float* nxt = buf0;
    for (int L = 0; L < NLAYERS; ++L) {
        gather_f32_kernel<<<gatherBlocks, 256, 0, stream>>>(cur, row_start, e_src, aggr);
        gemm_split_kernel<<<ggrid, 256, 0, stream>>>(aggr, cur,
                                                     Wh + (size_t)L * D * K2,
                                                     Wl + (size_t)L * D * K2,
                                                     b_conv + (size_t)L * D,
                                                     nxt);
        cur = nxt;
        nxt = (nxt == buf0) ? buf1 : buf0;
    }

    pool_seg_kernel<<<NGRAPH, 256, 0, stream>>>(cur, gstart, pooled);
    mlp1_gemm_kernel<<<dim3(NGRAPH / GBM, 1024 / GBN), 256, 0, stream>>>(pooled, W1h, W1l, b1, hbuf);
    mlp2_kernel<<<NGRAPH, 256, 0, stream>>>(hbuf, W2, b2, outp);
}